// Round 9
// baseline (1099.339 us; speedup 1.0000x reference)
//
#include <hip/hip_runtime.h>
#include <hip/hip_bf16.h>

#define WW 128
#define GG 64
#define GN_EPS 1e-5f
#define SCAN_B 1024

typedef __attribute__((ext_vector_type(8))) short short8;
typedef __attribute__((ext_vector_type(4))) float floatx4;

__device__ inline float bfbits2f(short v) {
    return __uint_as_float(((unsigned)(unsigned short)v) << 16);
}
__device__ inline short f2bfbits(float f) {
    __hip_bfloat16 h = __float2bfloat16(f);
    return *reinterpret_cast<short*>(&h);
}

// largest i in [0,32) with soff[i] <= e (soff ascending, e < soff[32])
__device__ inline int node_of(const int* soff, int e) {
    int lo = 0;
#pragma unroll
    for (int s = 16; s > 0; s >>= 1) {
        int cand = lo + s;                 // max reachable index = 31
        if (soff[cand] <= e) lo = cand;
    }
    return lo;
}

// ---------------- prep1: hist (4 edges/thread) U stats (64 rows) U cvt_w ----
__global__ __launch_bounds__(256) void prep1_kernel(
    const int* __restrict__ ei, int E, int* __restrict__ deg, int HB,
    const float* __restrict__ x, const int* __restrict__ batch, int N, int SB,
    float* __restrict__ gsum, float* __restrict__ gsumsq, float* __restrict__ gcnt,
    const float* __restrict__ w0, const float* __restrict__ w1,
    const float* __restrict__ w2, const float* __restrict__ w3,
    __hip_bfloat16* __restrict__ wdst)
{
    int bid = blockIdx.x;
    int tid = threadIdx.x;

    if (bid < HB) {
        int base = bid * 1024 + tid;
        int d0 = (base       < E) ? ei[(size_t)E + base]       : -1;
        int d1 = (base + 256 < E) ? ei[(size_t)E + base + 256] : -1;
        int d2 = (base + 512 < E) ? ei[(size_t)E + base + 512] : -1;
        int d3 = (base + 768 < E) ? ei[(size_t)E + base + 768] : -1;
        if (d0 >= 0) atomicAdd(&deg[d0], 1);
        if (d1 >= 0) atomicAdd(&deg[d1], 1);
        if (d2 >= 0) atomicAdd(&deg[d2], 1);
        if (d3 >= 0) atomicAdd(&deg[d3], 1);
        return;
    }
    if (bid < HB + SB) {
        int sb = bid - HB;
        int half = tid >> 7;
        int w = tid & 127;
        int row0 = sb * 64 + half * 32;
        if (row0 >= N) return;
        int row1 = min(row0 + 32, N);
        float s = 0.f, ss = 0.f;
        int cur = batch[row0];
        int cnt = 0;
        auto flush = [&]() {
            atomicAdd(&gsum[cur * WW + w], s);
            atomicAdd(&gsumsq[cur * WW + w], ss);
            if (w == 0) atomicAdd(&gcnt[cur], (float)cnt);
            s = 0.f; ss = 0.f; cnt = 0;
        };
        int i = row0;
        for (; i + 4 <= row1; i += 4) {
            int g0 = batch[i + 0], g1 = batch[i + 1], g2 = batch[i + 2], g3 = batch[i + 3];
            float v0 = x[(size_t)(i + 0) * WW + w];
            float v1 = x[(size_t)(i + 1) * WW + w];
            float v2 = x[(size_t)(i + 2) * WW + w];
            float v3 = x[(size_t)(i + 3) * WW + w];
            if (g0 != cur) { flush(); cur = g0; }
            s += v0; ss += v0 * v0; ++cnt;
            if (g1 != cur) { flush(); cur = g1; }
            s += v1; ss += v1 * v1; ++cnt;
            if (g2 != cur) { flush(); cur = g2; }
            s += v2; ss += v2 * v2; ++cnt;
            if (g3 != cur) { flush(); cur = g3; }
            s += v3; ss += v3 * v3; ++cnt;
        }
        for (; i < row1; ++i) {
            int g = batch[i];
            float v = x[(size_t)i * WW + w];
            if (g != cur) { flush(); cur = g; }
            s += v; ss += v * v; ++cnt;
        }
        flush();
        return;
    }
    int idx = (bid - HB - SB) * 256 + tid;        // 0 .. 65535
    int m = idx >> 14;
    int o = idx & 16383;
    const float* src = (m == 0) ? w0 : (m == 1) ? w1 : (m == 2) ? w2 : w3;
    wdst[idx] = __float2bfloat16(src[o]);
}

// ---------------- scan2: block-local scan U finalize (independent chains) ----
__global__ __launch_bounds__(SCAN_B) void scan2_kernel(
    const int* __restrict__ deg, int N, int* __restrict__ off, int* __restrict__ bsum, int P,
    const float* __restrict__ gsum, const float* __restrict__ gsumsq,
    const float* __restrict__ gcnt,
    const float* __restrict__ wgt, const float* __restrict__ bias,
    const float* __restrict__ ms,
    float* __restrict__ scalev, float* __restrict__ shiftv)
{
    int bid = blockIdx.x;
    int t = threadIdx.x;
    if (bid < P) {
        __shared__ int s[SCAN_B];
        int i = bid * SCAN_B + t;
        int v = (i < N) ? deg[i] : 0;
        s[t] = v; __syncthreads();
        for (int d = 1; d < SCAN_B; d <<= 1) {
            int tmp = (t >= d) ? s[t - d] : 0;
            __syncthreads();
            s[t] += tmp;
            __syncthreads();
        }
        if (i < N) off[i] = s[t] - v;
        if (t == SCAN_B - 1) bsum[bid] = s[t];
        return;
    }
    int idx = (bid - P) * SCAN_B + t;
    if (idx >= GG * WW) return;
    int g = idx >> 7, w = idx & (WW - 1);
    float cnt = gcnt[g];
    float inv = cnt > 0.f ? 1.f / cnt : 0.f;
    float mean = gsum[idx] * inv;
    float msw = ms[w];
    float var = gsumsq[idx] * inv - mean * mean * msw * (2.f - msw);
    var = fmaxf(var, 0.f);
    float sc = wgt[w] * rsqrtf(var + GN_EPS);
    scalev[idx] = sc;
    shiftv[idx] = bias[w] - sc * msw * mean;
}

// add_offsets v2: absorbs scan_partials (each block reduces bsum[0..bid))
__global__ __launch_bounds__(SCAN_B) void add_offsets2(
    int* __restrict__ off, const int* __restrict__ bsum, int N)
{
    __shared__ int red[SCAN_B];
    int t = threadIdx.x;
    red[t] = (t < blockIdx.x) ? bsum[t] : 0;
    __syncthreads();
    for (int s = SCAN_B / 2; s > 0; s >>= 1) {
        if (t < s) red[t] += red[t + s];
        __syncthreads();
    }
    int i = blockIdx.x * SCAN_B + t;
    if (i < N) off[i] += red[0];
}

// ---------------- place_norm: place (4 edges/thread) U normalize ----------
// place dep (off) completes in add_offsets2; normalize dep (scalev/shiftv)
// completed in scan2 -> both runnable here; normalize's streaming blocks
// hide place's latency-bound scatter.
__global__ __launch_bounds__(256) void place_norm_kernel(
    const int* __restrict__ ei, const float* __restrict__ ew,
    const int* __restrict__ off, int* __restrict__ cursor,
    int2* __restrict__ ebuf, int E, int PB,
    const float* __restrict__ x, const int* __restrict__ batch,
    const float* __restrict__ scalev, const float* __restrict__ shiftv,
    __hip_bfloat16* __restrict__ xn, int N)
{
    int bid = blockIdx.x;
    int tid = threadIdx.x;

    if (bid < PB) {
        int base = bid * 1024 + tid;
        int dstv[4], srcv[4];
        float wv[4];
        int slot[4];
#pragma unroll
        for (int i = 0; i < 4; ++i) {
            int e = base + i * 256;
            dstv[i] = (e < E) ? ei[(size_t)E + e] : -1;
        }
#pragma unroll
        for (int i = 0; i < 4; ++i) {
            int e = base + i * 256;
            if (e < E) { srcv[i] = ei[e]; wv[i] = ew[e]; }
        }
#pragma unroll
        for (int i = 0; i < 4; ++i)
            if (dstv[i] >= 0) slot[i] = off[dstv[i]] + atomicAdd(&cursor[dstv[i]], 1);
#pragma unroll
        for (int i = 0; i < 4; ++i)
            if (dstv[i] >= 0) {
                unsigned long long v = (unsigned)srcv[i]
                    | ((unsigned long long)__float_as_uint(wv[i]) << 32);
                __builtin_nontemporal_store(v, (unsigned long long*)&ebuf[slot[i]]);
            }
        return;
    }
    // ---- normalize: one thread per 8 elems, 16B stores ----
    size_t nt = (size_t)(bid - PB) * 256 + tid;
    if (nt >= (size_t)N * (WW / 8)) return;
    int row = (int)(nt >> 4);
    int c8 = (int)(nt & 15) * 8;
    int g = batch[row];
    const float* xb = x + (size_t)row * WW + c8;
    const float* scb = scalev + (size_t)g * WW + c8;
    const float* shb = shiftv + (size_t)g * WW + c8;
    float4 v0 = *(const float4*)(xb);
    float4 v1 = *(const float4*)(xb + 4);
    float4 sc0 = *(const float4*)(scb);
    float4 sc1 = *(const float4*)(scb + 4);
    float4 sh0 = *(const float4*)(shb);
    float4 sh1 = *(const float4*)(shb + 4);
    union { short s[8]; uint4 u; } pk;
    pk.s[0] = f2bfbits(sc0.x * v0.x + sh0.x);
    pk.s[1] = f2bfbits(sc0.y * v0.y + sh0.y);
    pk.s[2] = f2bfbits(sc0.z * v0.z + sh0.z);
    pk.s[3] = f2bfbits(sc0.w * v0.w + sh0.w);
    pk.s[4] = f2bfbits(sc1.x * v1.x + sh1.x);
    pk.s[5] = f2bfbits(sc1.y * v1.y + sh1.y);
    pk.s[6] = f2bfbits(sc1.z * v1.z + sh1.z);
    pk.s[7] = f2bfbits(sc1.w * v1.w + sh1.w);
    *(uint4*)(xn + (size_t)row * WW + c8) = pk.u;
}

// ---------------- fused gather+GEMM v12: edge-parallel balanced gather ------
// R7/R8: gather phase is straggler-bound (block time = ceil(max_deg/4) rounds,
// ~2.3x mean work). v12 makes it edge-parallel: 32 groups stride the staged
// edge list (e = g, g+32, ..., 4-deep unroll -> ceil(ne/128) ~= 2 uniform
// rounds), binary-search dst node in staged soff[33], accumulate w*x into
// shared fp32 agg[32][128] via LDS atomics. Bank discipline: thread owns
// channel chunks {sub, sub+8}; atomic order rotated by group-in-wave ->
// <=2-way conflicts (free, m136). Fallback per-node path for ne>512 (rare).
// A2 staging, W-frag layout (adjacent-pair cols), MFMA, epilogue unchanged.
// LDS 36.1 KB -> 4 blocks/CU.
// LDS swizzle (involution): A1 slot s of row r holds chunk s^(r&15).
// C/D layout: col=lane&15, row=(lane>>4)*4+reg (m89-verified).
template <bool OUT_BF16>
__global__ __launch_bounds__(256, 4) void fused_kernel(
    const __hip_bfloat16* __restrict__ X,
    const int2* __restrict__ ebuf, const int* __restrict__ off,
    const int* __restrict__ deg,
    const __hip_bfloat16* __restrict__ Wrel, const __hip_bfloat16* __restrict__ Wroot,
    const float* __restrict__ bias, const float* __restrict__ resid,
    void* __restrict__ outv, int N, int leaky)
{
    __shared__ __align__(16) __hip_bfloat16 smem[2 * 32 * 128];   // 16 KB (A1|A2)
    __shared__ __align__(16) float agg[32 * 128];                 // 16 KB fp32
    __shared__ __align__(16) int2 eshare[512];                    // 4 KB
    __shared__ int soff[33];
    int tid = threadIdx.x;
    int wave = tid >> 6, lane = tid & 63;
    int q = lane >> 4, r16 = lane & 15;
    int rb = blockIdx.x * 32;

    // ---- (1a) A2 staging: 8 x 1KB, 2 per wave (async) ----
#pragma unroll
    for (int s = 0; s < 2; ++s) {
        int t = wave * 2 + s;
        int rloc = t * 4 + (lane >> 4);
        int c = (lane & 15) ^ (rloc & 15);        // pre-swizzled global chunk
        int grow = rb + rloc; if (grow >= N) grow = N - 1;
        const __hip_bfloat16* g = X + (size_t)grow * WW + c * 8;
        __hip_bfloat16* l = smem + 4096 + t * 512;
        __builtin_amdgcn_global_load_lds(
            (const __attribute__((address_space(1))) void*)g,
            (__attribute__((address_space(3))) void*)l, 16, 0, 0);
    }

    // ---- (1b) ebuf slice staging ----
    int endn = min(rb + 32, N) - 1;
    int e0 = off[rb];
    int ne = off[endn] + deg[endn] - e0;
    int nstage = min(ne, 512);
    {
        int pairs = (nstage + 1) >> 1;
        if (tid < pairs) {
            const int2* g = ebuf + e0 + 2 * tid;
            int2* l = eshare + 2 * (wave * 64);
            __builtin_amdgcn_global_load_lds(
                (const __attribute__((address_space(1))) void*)g,
                (__attribute__((address_space(3))) void*)l, 16, 0, 0);
        }
    }
    // ---- (1c) node-offset table (33 entries, local to block) ----
    if (tid <= 32) {
        int n = rb + tid;
        soff[tid] = (n < N) ? (off[n] - e0) : ne;
    }
    // ---- (1d) zero agg (stride-256: bank = tid&31, conflict-free) ----
#pragma unroll
    for (int j = 0; j < 16; ++j) agg[tid + 256 * j] = 0.f;

    __syncthreads();   // vmcnt+lgkm drained: A2, eshare, soff, agg ready

    int g8 = tid >> 3;                 // group 0..31
    int sub = tid & 7;
    int gw = g8 & 7;                   // group-in-wave (bank rotation)

    if (ne <= 512) {
        // ---- (2) balanced edge loop: 4-deep, stride 128 ----
        for (int e = g8; e < ne; e += 128) {
            int c1 = e + 32, c2 = e + 64, c3 = e + 96;
            bool v1 = c1 < ne, v2 = c2 < ne, v3 = c3 < ne;
            int f1 = v1 ? c1 : e, f2 = v2 ? c2 : e, f3 = v3 ? c3 : e;
            int2 p0 = eshare[e];
            int2 p1 = eshare[f1];
            int2 p2 = eshare[f2];
            int2 p3 = eshare[f3];
            const __hip_bfloat16* r0 = X + (size_t)p0.x * WW + sub * 8;
            const __hip_bfloat16* r1 = X + (size_t)p1.x * WW + sub * 8;
            const __hip_bfloat16* r2 = X + (size_t)p2.x * WW + sub * 8;
            const __hip_bfloat16* r3 = X + (size_t)p3.x * WW + sub * 8;
            short8 a0 = *(const short8*)(r0);
            short8 b0 = *(const short8*)(r0 + 64);
            short8 a1 = *(const short8*)(r1);
            short8 b1 = *(const short8*)(r1 + 64);
            short8 a2 = *(const short8*)(r2);
            short8 b2 = *(const short8*)(r2 + 64);
            short8 a3 = *(const short8*)(r3);
            short8 b3 = *(const short8*)(r3 + 64);
            float w0 = __int_as_float(p0.y);
            float w1 = __int_as_float(p1.y);
            float w2 = __int_as_float(p2.y);
            float w3 = __int_as_float(p3.y);
            int n0 = node_of(soff, e);
            int n1 = node_of(soff, f1);
            int n2 = node_of(soff, f2);
            int n3 = node_of(soff, f3);
            float* d0 = &agg[n0 * 128 + sub * 8];
            float* d1 = &agg[n1 * 128 + sub * 8];
            float* d2 = &agg[n2 * 128 + sub * 8];
            float* d3 = &agg[n3 * 128 + sub * 8];
#pragma unroll
            for (int jj = 0; jj < 8; ++jj) {
                int j = (jj + gw) & 7;             // rotate: <=2-way banks
                atomicAdd(d0 + j,      w0 * bfbits2f(a0[j]));
                atomicAdd(d0 + 64 + j, w0 * bfbits2f(b0[j]));
                if (v1) { atomicAdd(d1 + j,      w1 * bfbits2f(a1[j]));
                          atomicAdd(d1 + 64 + j, w1 * bfbits2f(b1[j])); }
                if (v2) { atomicAdd(d2 + j,      w2 * bfbits2f(a2[j]));
                          atomicAdd(d2 + 64 + j, w2 * bfbits2f(b2[j])); }
                if (v3) { atomicAdd(d3 + j,      w3 * bfbits2f(a3[j]));
                          atomicAdd(d3 + 64 + j, w3 * bfbits2f(b3[j])); }
            }
        }
    } else {
        // ---- fallback (ne > 512, ~never): per-node serial, plain stores ----
        int node = rb + g8;
        float a16[16];
#pragma unroll
        for (int j = 0; j < 16; ++j) a16[j] = 0.f;
        if (node < N) {
            int start = off[node];
            int d = deg[node];
            for (int k = 0; k < d; k += 2) {
                int k1 = (k + 1 < d) ? k + 1 : k;
                int2 p0 = ebuf[start + k];
                int2 p1 = ebuf[start + k1];
                const __hip_bfloat16* r0 = X + (size_t)p0.x * WW + sub * 8;
                const __hip_bfloat16* r1 = X + (size_t)p1.x * WW + sub * 8;
                short8 a0 = *(const short8*)(r0);
                short8 b0 = *(const short8*)(r0 + 64);
                short8 a1 = *(const short8*)(r1);
                short8 b1 = *(const short8*)(r1 + 64);
                float w0 = __int_as_float(p0.y);
                float w1 = (k + 1 < d) ? __int_as_float(p1.y) : 0.f;
#pragma unroll
                for (int j = 0; j < 8; ++j) {
                    a16[j]     += w0 * bfbits2f(a0[j]) + w1 * bfbits2f(a1[j]);
                    a16[8 + j] += w0 * bfbits2f(b0[j]) + w1 * bfbits2f(b1[j]);
                }
            }
            float* dstf = &agg[g8 * 128 + sub * 8];
#pragma unroll
            for (int j = 0; j < 8; ++j) {
                dstf[j]      = a16[j];
                dstf[64 + j] = a16[8 + j];
            }
        }
    }

    // ---- W fragments: adjacent-pair cols (wave*32 + 2*r16 + tt) ----
    short8 wf[8][2];
#pragma unroll
    for (int kc = 0; kc < 8; ++kc) {
        const __hip_bfloat16* Wsel = (kc < 4) ? Wrel : Wroot;
        int koff = (kc & 3) * 32 + q * 8;
#pragma unroll
        for (int tt = 0; tt < 2; ++tt) {
            int col = wave * 32 + 2 * r16 + tt;
            wf[kc][tt] = *(const short8*)(Wsel + ((size_t)col * WW + koff));
        }
    }
    float bcol[2];
#pragma unroll
    for (int tt = 0; tt < 2; ++tt) bcol[tt] = bias[wave * 32 + 2 * r16 + tt];

    __syncthreads();   // agg complete

    // ---- (3) agg fp32 -> bf16 swizzled A1 ----
    {
        int r = tid >> 3;
        short8 pk0, pk1;
#pragma unroll
        for (int j = 0; j < 8; ++j) {
            pk0[j] = f2bfbits(agg[r * 128 + sub * 16 + j]);
            pk1[j] = f2bfbits(agg[r * 128 + sub * 16 + 8 + j]);
        }
        int s0 = (2 * sub)     ^ (r & 15);
        int s1 = (2 * sub + 1) ^ (r & 15);
        *(short8*)(smem + r * 128 + s0 * 8) = pk0;
        *(short8*)(smem + r * 128 + s1 * 8) = pk1;
    }
    __syncthreads();   // A1 ready (A2 resident since barrier #1)

    // ---- (5) MFMA: kc<4 A1*Wrel, kc>=4 A2*Wroot ----
    floatx4 acc[2][2];
#pragma unroll
    for (int r = 0; r < 2; ++r)
#pragma unroll
        for (int tt = 0; tt < 2; ++tt) acc[r][tt] = (floatx4){0.f, 0.f, 0.f, 0.f};

#pragma unroll
    for (int kc = 0; kc < 8; ++kc) {
        int m = kc >> 2;
        short8 af[2];
#pragma unroll
        for (int r = 0; r < 2; ++r) {
            int row = r * 16 + r16;
            int slot = ((kc & 3) * 4 + q) ^ r16;       // row&15 == r16
            af[r] = *(const short8*)(&smem[m * 4096 + row * 128 + slot * 8]);
        }
#pragma unroll
        for (int r = 0; r < 2; ++r) {
            acc[r][0] = __builtin_amdgcn_mfma_f32_16x16x32_bf16(af[r], wf[kc][0], acc[r][0], 0, 0, 0);
            acc[r][1] = __builtin_amdgcn_mfma_f32_16x16x32_bf16(af[r], wf[kc][1], acc[r][1], 0, 0, 0);
        }
    }

    // ---- epilogue: packed adjacent-col stores ----
    int colb = wave * 32 + 2 * r16;
#pragma unroll
    for (int r = 0; r < 2; ++r)
#pragma unroll
        for (int rr = 0; rr < 4; ++rr) {
            int row = rb + r * 16 + q * 4 + rr;
            if (row < N) {
                float v0 = acc[r][0][rr] + bcol[0];
                float v1 = acc[r][1][rr] + bcol[1];
                if (leaky) {
                    v0 = v0 >= 0.f ? v0 : 0.1f * v0;
                    v1 = v1 >= 0.f ? v1 : 0.1f * v1;
                }
                if (OUT_BF16) {
                    __hip_bfloat162 o;
                    o.x = __float2bfloat16(v0);
                    o.y = __float2bfloat16(v1);
                    *(__hip_bfloat162*)((__hip_bfloat16*)outv + (size_t)row * WW + colb) = o;
                } else {
                    float2 rv = *(const float2*)(resid + (size_t)row * WW + colb);
                    float2 o;
                    o.x = v0 + rv.x;
                    o.y = v1 + rv.y;
                    *(float2*)((float*)outv + (size_t)row * WW + colb) = o;
                }
            }
        }
}

extern "C" void kernel_launch(void* const* d_in, const int* in_sizes, int n_in,
                              void* d_out, int out_size, void* d_ws, size_t ws_size,
                              hipStream_t stream) {
    const float* x      = (const float*)d_in[0];
    const int*   ei     = (const int*)d_in[1];
    const float* ew     = (const float*)d_in[2];
    const int*   batch  = (const int*)d_in[3];
    const float* gnw    = (const float*)d_in[4];
    const float* gnb    = (const float*)d_in[5];
    const float* gnm    = (const float*)d_in[6];
    const float* Wrel1  = (const float*)d_in[7];
    const float* brel1  = (const float*)d_in[8];
    const float* Wroot1 = (const float*)d_in[9];
    const float* Wrel2  = (const float*)d_in[10];
    const float* brel2  = (const float*)d_in[11];
    const float* Wroot2 = (const float*)d_in[12];

    int N = in_sizes[0] / WW;
    int E = in_sizes[1] / 2;
    int P = (N + SCAN_B - 1) / SCAN_B;           // 98
    int ntiles = (N + 31) / 32;                  // 3125
    int HB = (E + 1023) / 1024;                  // hist blocks
    int SB = (N + 63) / 64;                      // stats blocks
    int PB = (E + 1023) / 1024;                  // place blocks
    int FB2 = (GG * WW + SCAN_B - 1) / SCAN_B;   // finalize blocks @1024 (8)
    int NB = (int)(((size_t)N * (WW / 8) + 255) / 256);   // normalize blocks

    // workspace layout (8-byte aligned):
    // xn | y1 (bf16 N*W each) | Wb (bf16 4*W*W) | ebuf (int2 E)
    // | deg | cursor | gsum | gsumsq | gcnt | scalev | shiftv | off | bsum
    __hip_bfloat16* xn = (__hip_bfloat16*)d_ws;
    __hip_bfloat16* y1 = xn + (size_t)N * WW;
    __hip_bfloat16* Wb = y1 + (size_t)N * WW;
    int2* ebuf   = (int2*)(Wb + 4 * WW * WW);
    int*  deg    = (int*)(ebuf + E);
    int*  cursor = deg + N;
    float* gsum   = (float*)(cursor + N);
    float* gsumsq = gsum + GG * WW;
    float* gcnt   = gsumsq + GG * WW;
    float* scalev = gcnt + GG;
    float* shiftv = scalev + GG * WW;
    int*  off    = (int*)(shiftv + GG * WW);
    int*  bsum   = off + N;

    hipMemsetAsync(deg, 0, ((size_t)2 * N + 2 * GG * WW + GG) * sizeof(int), stream);

    // ---- prep1: hist U stats U cvt_w ----
    prep1_kernel<<<HB + SB + 256, 256, 0, stream>>>(
        ei, E, deg, HB,
        x, batch, N, SB, gsum, gsumsq, gcnt,
        Wrel1, Wroot1, Wrel2, Wroot2, Wb);

    // ---- scan2: block scan U finalize ----
    scan2_kernel<<<P + FB2, SCAN_B, 0, stream>>>(
        deg, N, off, bsum, P,
        gsum, gsumsq, gcnt, gnw, gnb, gnm, scalev, shiftv);

    add_offsets2<<<P, SCAN_B, 0, stream>>>(off, bsum, N);

    // ---- place U normalize ----
    place_norm_kernel<<<PB + NB, 256, 0, stream>>>(
        ei, ew, off, cursor, ebuf, E, PB,
        x, batch, scalev, shiftv, xn, N);

    // ---- layer 1: fused gather+GEMM (+bias+leaky) ----
    fused_kernel<true><<<ntiles, 256, 0, stream>>>(
        xn, ebuf, off, deg, Wb, Wb + WW * WW, brel1, nullptr, y1, N, 1);

    // ---- layer 2: fused gather+GEMM (+bias+residual) ----
    fused_kernel<false><<<ntiles, 256, 0, stream>>>(
        y1, ebuf, off, deg, Wb + 2 * WW * WW, Wb + 3 * WW * WW, brel2, x, d_out, N, 0);
}

// Round 10
// 312.717 us; speedup vs baseline: 3.5154x; 3.5154x over previous
//
#include <hip/hip_runtime.h>
#include <hip/hip_bf16.h>

#define WW 128
#define GG 64
#define GN_EPS 1e-5f
#define SCAN_B 1024

typedef __attribute__((ext_vector_type(8))) short short8;
typedef __attribute__((ext_vector_type(4))) float floatx4;

__device__ inline float bfbits2f(short v) {
    return __uint_as_float(((unsigned)(unsigned short)v) << 16);
}
__device__ inline short f2bfbits(float f) {
    __hip_bfloat16 h = __float2bfloat16(f);
    return *reinterpret_cast<short*>(&h);
}

// ---------------- prep1: hist (4 edges/thread) U stats (64 rows) U cvt_w ----
__global__ __launch_bounds__(256) void prep1_kernel(
    const int* __restrict__ ei, int E, int* __restrict__ deg, int HB,
    const float* __restrict__ x, const int* __restrict__ batch, int N, int SB,
    float* __restrict__ gsum, float* __restrict__ gsumsq, float* __restrict__ gcnt,
    const float* __restrict__ w0, const float* __restrict__ w1,
    const float* __restrict__ w2, const float* __restrict__ w3,
    __hip_bfloat16* __restrict__ wdst)
{
    int bid = blockIdx.x;
    int tid = threadIdx.x;

    if (bid < HB) {
        int base = bid * 1024 + tid;
        int d0 = (base       < E) ? ei[(size_t)E + base]       : -1;
        int d1 = (base + 256 < E) ? ei[(size_t)E + base + 256] : -1;
        int d2 = (base + 512 < E) ? ei[(size_t)E + base + 512] : -1;
        int d3 = (base + 768 < E) ? ei[(size_t)E + base + 768] : -1;
        if (d0 >= 0) atomicAdd(&deg[d0], 1);
        if (d1 >= 0) atomicAdd(&deg[d1], 1);
        if (d2 >= 0) atomicAdd(&deg[d2], 1);
        if (d3 >= 0) atomicAdd(&deg[d3], 1);
        return;
    }
    if (bid < HB + SB) {
        int sb = bid - HB;
        int half = tid >> 7;
        int w = tid & 127;
        int row0 = sb * 64 + half * 32;
        if (row0 >= N) return;
        int row1 = min(row0 + 32, N);
        float s = 0.f, ss = 0.f;
        int cur = batch[row0];
        int cnt = 0;
        auto flush = [&]() {
            atomicAdd(&gsum[cur * WW + w], s);
            atomicAdd(&gsumsq[cur * WW + w], ss);
            if (w == 0) atomicAdd(&gcnt[cur], (float)cnt);
            s = 0.f; ss = 0.f; cnt = 0;
        };
        int i = row0;
        for (; i + 4 <= row1; i += 4) {
            int g0 = batch[i + 0], g1 = batch[i + 1], g2 = batch[i + 2], g3 = batch[i + 3];
            float v0 = x[(size_t)(i + 0) * WW + w];
            float v1 = x[(size_t)(i + 1) * WW + w];
            float v2 = x[(size_t)(i + 2) * WW + w];
            float v3 = x[(size_t)(i + 3) * WW + w];
            if (g0 != cur) { flush(); cur = g0; }
            s += v0; ss += v0 * v0; ++cnt;
            if (g1 != cur) { flush(); cur = g1; }
            s += v1; ss += v1 * v1; ++cnt;
            if (g2 != cur) { flush(); cur = g2; }
            s += v2; ss += v2 * v2; ++cnt;
            if (g3 != cur) { flush(); cur = g3; }
            s += v3; ss += v3 * v3; ++cnt;
        }
        for (; i < row1; ++i) {
            int g = batch[i];
            float v = x[(size_t)i * WW + w];
            if (g != cur) { flush(); cur = g; }
            s += v; ss += v * v; ++cnt;
        }
        flush();
        return;
    }
    int idx = (bid - HB - SB) * 256 + tid;        // 0 .. 65535
    int m = idx >> 14;
    int o = idx & 16383;
    const float* src = (m == 0) ? w0 : (m == 1) ? w1 : (m == 2) ? w2 : w3;
    wdst[idx] = __float2bfloat16(src[o]);
}

// ---------------- scan2: block-local scan U finalize (independent chains) ----
__global__ __launch_bounds__(SCAN_B) void scan2_kernel(
    const int* __restrict__ deg, int N, int* __restrict__ off, int* __restrict__ bsum, int P,
    const float* __restrict__ gsum, const float* __restrict__ gsumsq,
    const float* __restrict__ gcnt,
    const float* __restrict__ wgt, const float* __restrict__ bias,
    const float* __restrict__ ms,
    float* __restrict__ scalev, float* __restrict__ shiftv)
{
    int bid = blockIdx.x;
    int t = threadIdx.x;
    if (bid < P) {
        __shared__ int s[SCAN_B];
        int i = bid * SCAN_B + t;
        int v = (i < N) ? deg[i] : 0;
        s[t] = v; __syncthreads();
        for (int d = 1; d < SCAN_B; d <<= 1) {
            int tmp = (t >= d) ? s[t - d] : 0;
            __syncthreads();
            s[t] += tmp;
            __syncthreads();
        }
        if (i < N) off[i] = s[t] - v;
        if (t == SCAN_B - 1) bsum[bid] = s[t];
        return;
    }
    int idx = (bid - P) * SCAN_B + t;
    if (idx >= GG * WW) return;
    int g = idx >> 7, w = idx & (WW - 1);
    float cnt = gcnt[g];
    float inv = cnt > 0.f ? 1.f / cnt : 0.f;
    float mean = gsum[idx] * inv;
    float msw = ms[w];
    float var = gsumsq[idx] * inv - mean * mean * msw * (2.f - msw);
    var = fmaxf(var, 0.f);
    float sc = wgt[w] * rsqrtf(var + GN_EPS);
    scalev[idx] = sc;
    shiftv[idx] = bias[w] - sc * msw * mean;
}

// add_offsets v2: absorbs scan_partials (each block reduces bsum[0..bid))
__global__ __launch_bounds__(SCAN_B) void add_offsets2(
    int* __restrict__ off, const int* __restrict__ bsum, int N)
{
    __shared__ int red[SCAN_B];
    int t = threadIdx.x;
    red[t] = (t < blockIdx.x) ? bsum[t] : 0;
    __syncthreads();
    for (int s = SCAN_B / 2; s > 0; s >>= 1) {
        if (t < s) red[t] += red[t + s];
        __syncthreads();
    }
    int i = blockIdx.x * SCAN_B + t;
    if (i < N) off[i] += red[0];
}

// ---------------- place_norm: place (4 edges/thread) U normalize ----------
__global__ __launch_bounds__(256) void place_norm_kernel(
    const int* __restrict__ ei, const float* __restrict__ ew,
    const int* __restrict__ off, int* __restrict__ cursor,
    int2* __restrict__ ebuf, int E, int PB,
    const float* __restrict__ x, const int* __restrict__ batch,
    const float* __restrict__ scalev, const float* __restrict__ shiftv,
    __hip_bfloat16* __restrict__ xn, int N)
{
    int bid = blockIdx.x;
    int tid = threadIdx.x;

    if (bid < PB) {
        int base = bid * 1024 + tid;
        int dstv[4], srcv[4];
        float wv[4];
        int slot[4];
#pragma unroll
        for (int i = 0; i < 4; ++i) {
            int e = base + i * 256;
            dstv[i] = (e < E) ? ei[(size_t)E + e] : -1;
        }
#pragma unroll
        for (int i = 0; i < 4; ++i) {
            int e = base + i * 256;
            if (e < E) { srcv[i] = ei[e]; wv[i] = ew[e]; }
        }
#pragma unroll
        for (int i = 0; i < 4; ++i)
            if (dstv[i] >= 0) slot[i] = off[dstv[i]] + atomicAdd(&cursor[dstv[i]], 1);
#pragma unroll
        for (int i = 0; i < 4; ++i)
            if (dstv[i] >= 0) {
                unsigned long long v = (unsigned)srcv[i]
                    | ((unsigned long long)__float_as_uint(wv[i]) << 32);
                __builtin_nontemporal_store(v, (unsigned long long*)&ebuf[slot[i]]);
            }
        return;
    }
    // ---- normalize: one thread per 8 elems, 16B stores ----
    size_t nt = (size_t)(bid - PB) * 256 + tid;
    if (nt >= (size_t)N * (WW / 8)) return;
    int row = (int)(nt >> 4);
    int c8 = (int)(nt & 15) * 8;
    int g = batch[row];
    const float* xb = x + (size_t)row * WW + c8;
    const float* scb = scalev + (size_t)g * WW + c8;
    const float* shb = shiftv + (size_t)g * WW + c8;
    float4 v0 = *(const float4*)(xb);
    float4 v1 = *(const float4*)(xb + 4);
    float4 sc0 = *(const float4*)(scb);
    float4 sc1 = *(const float4*)(scb + 4);
    float4 sh0 = *(const float4*)(shb);
    float4 sh1 = *(const float4*)(shb + 4);
    union { short s[8]; uint4 u; } pk;
    pk.s[0] = f2bfbits(sc0.x * v0.x + sh0.x);
    pk.s[1] = f2bfbits(sc0.y * v0.y + sh0.y);
    pk.s[2] = f2bfbits(sc0.z * v0.z + sh0.z);
    pk.s[3] = f2bfbits(sc0.w * v0.w + sh0.w);
    pk.s[4] = f2bfbits(sc1.x * v1.x + sh1.x);
    pk.s[5] = f2bfbits(sc1.y * v1.y + sh1.y);
    pk.s[6] = f2bfbits(sc1.z * v1.z + sh1.z);
    pk.s[7] = f2bfbits(sc1.w * v1.w + sh1.w);
    *(uint4*)(xn + (size_t)row * WW + c8) = pk.u;
}

// ---------------- fused gather+GEMM v11 (R8-verified, 63 us) -----------------
// REVERT of R9's edge-parallel v12: LDS atomics serialized on same-dst
// addresses (5.4M bank conflicts, 7x regression). v11 is the measured best:
// LDS-staged edge slice + per-node 4-wide gather + A2 via global_load_lds +
// MFMA. LDS swizzle (involution): slot s of row r holds chunk s^(r&15).
// C/D layout: col=lane&15, row=(lane>>4)*4+reg (m89-verified).
template <bool OUT_BF16>
__global__ __launch_bounds__(256, 4) void fused_kernel(
    const __hip_bfloat16* __restrict__ X,
    const int2* __restrict__ ebuf, const int* __restrict__ off,
    const int* __restrict__ deg,
    const __hip_bfloat16* __restrict__ Wrel, const __hip_bfloat16* __restrict__ Wroot,
    const float* __restrict__ bias, const float* __restrict__ resid,
    void* __restrict__ outv, int N, int leaky)
{
    __shared__ __align__(16) __hip_bfloat16 smem[2 * 32 * 128];   // 16 KB
    __shared__ __align__(16) int2 eshare[512];                    // 4 KB
    int tid = threadIdx.x;
    int wave = tid >> 6, lane = tid & 63;
    int q = lane >> 4, r16 = lane & 15;
    int rb = blockIdx.x * 32;

    // ---- (1a) A2 staging: 8 x 1KB instructions, 2 per wave (async) ----
#pragma unroll
    for (int s = 0; s < 2; ++s) {
        int t = wave * 2 + s;                     // 0..7, rows t*4..t*4+3
        int rloc = t * 4 + (lane >> 4);
        int c = (lane & 15) ^ (rloc & 15);        // pre-swizzled global chunk
        int grow = rb + rloc; if (grow >= N) grow = N - 1;
        const __hip_bfloat16* g = X + (size_t)grow * WW + c * 8;
        __hip_bfloat16* l = smem + 4096 + t * 512;   // linear LDS dest
        __builtin_amdgcn_global_load_lds(
            (const __attribute__((address_space(1))) void*)g,
            (__attribute__((address_space(3))) void*)l, 16, 0, 0);
    }

    // ---- (1b) ebuf slice staging: entries [e0, e0+nstage) -> eshare ----
    int endn = min(rb + 32, N) - 1;
    int e0 = off[rb];
    int ne = off[endn] + deg[endn] - e0;
    int nstage = min(ne, 512);
    {
        int pairs = (nstage + 1) >> 1;            // <= 256: one instr/thread
        if (tid < pairs) {
            const int2* g = ebuf + e0 + 2 * tid;
            int2* l = eshare + 2 * (wave * 64);
            __builtin_amdgcn_global_load_lds(
                (const __attribute__((address_space(1))) void*)g,
                (__attribute__((address_space(3))) void*)l, 16, 0, 0);
        }
    }
    __syncthreads();   // vmcnt(0): A2 + edge slice resident

    // ---- (2) gather: node = rb + tid>>3, cols (tid&7)*16..+15 ----
    int node = rb + (tid >> 3);
    int nc = node < N ? node : N - 1;
    int start = off[nc];
    int d = (node < N) ? deg[nc] : 0;
    int lb = start - e0;                          // local index into eshare
    int sub = tid & 7;
    float a16[16];
#pragma unroll
    for (int j = 0; j < 16; ++j) a16[j] = 0.f;
    int last = d - 1;                             // d==0 -> loop skipped
    for (int k = 0; k <= last; k += 4) {
        int j1 = min(k + 1, last);
        int j2 = min(k + 2, last);
        int j3 = min(k + 3, last);
        int2 p0, p1, p2, p3;
        if (lb + j3 < nstage) {                   // common case: all staged
            p0 = eshare[lb + k];
            p1 = eshare[lb + j1];
            p2 = eshare[lb + j2];
            p3 = eshare[lb + j3];
        } else {                                  // ~never (block ne > 512)
            p0 = (lb + k  < nstage) ? eshare[lb + k]  : ebuf[start + k];
            p1 = (lb + j1 < nstage) ? eshare[lb + j1] : ebuf[start + j1];
            p2 = (lb + j2 < nstage) ? eshare[lb + j2] : ebuf[start + j2];
            p3 = (lb + j3 < nstage) ? eshare[lb + j3] : ebuf[start + j3];
        }
        const __hip_bfloat16* r0 = X + (size_t)p0.x * WW + sub * 16;
        const __hip_bfloat16* r1 = X + (size_t)p1.x * WW + sub * 16;
        const __hip_bfloat16* r2 = X + (size_t)p2.x * WW + sub * 16;
        const __hip_bfloat16* r3 = X + (size_t)p3.x * WW + sub * 16;
        short8 a0 = *(const short8*)(r0);
        short8 b0 = *(const short8*)(r0 + 8);
        short8 a1 = *(const short8*)(r1);
        short8 b1 = *(const short8*)(r1 + 8);
        short8 a2 = *(const short8*)(r2);
        short8 b2 = *(const short8*)(r2 + 8);
        short8 a3 = *(const short8*)(r3);
        short8 b3 = *(const short8*)(r3 + 8);
        float w0 = __int_as_float(p0.y);
        float w1 = (k + 1 <= last) ? __int_as_float(p1.y) : 0.f;
        float w2 = (k + 2 <= last) ? __int_as_float(p2.y) : 0.f;
        float w3 = (k + 3 <= last) ? __int_as_float(p3.y) : 0.f;
#pragma unroll
        for (int j = 0; j < 8; ++j) {
            a16[j]     += w0 * bfbits2f(a0[j]) + w1 * bfbits2f(a1[j]);
            a16[8 + j] += w0 * bfbits2f(b0[j]) + w1 * bfbits2f(b1[j]);
            a16[j]     += w2 * bfbits2f(a2[j]) + w3 * bfbits2f(a3[j]);
            a16[8 + j] += w2 * bfbits2f(b2[j]) + w3 * bfbits2f(b3[j]);
        }
    }

    // ---- (3) agg -> A1 LDS region, swizzled (chunks 2*sub, 2*sub+1) ----
    {
        int r = tid >> 3;                          // local row 0..31
        short8 pk0, pk1;
#pragma unroll
        for (int j = 0; j < 8; ++j) {
            pk0[j] = f2bfbits(a16[j]);
            pk1[j] = f2bfbits(a16[8 + j]);
        }
        int s0 = (2 * sub)     ^ (r & 15);
        int s1 = (2 * sub + 1) ^ (r & 15);
        *(short8*)(smem + r * 128 + s0 * 8) = pk0;
        *(short8*)(smem + r * 128 + s1 * 8) = pk1;
    }

    // ---- W fragments: adjacent-pair cols (wave*32 + 2*r16 + tt) ----
    short8 wf[8][2];
#pragma unroll
    for (int kc = 0; kc < 8; ++kc) {
        const __hip_bfloat16* Wsel = (kc < 4) ? Wrel : Wroot;
        int koff = (kc & 3) * 32 + q * 8;
#pragma unroll
        for (int tt = 0; tt < 2; ++tt) {
            int col = wave * 32 + 2 * r16 + tt;
            wf[kc][tt] = *(const short8*)(Wsel + ((size_t)col * WW + koff));
        }
    }
    float bcol[2];
#pragma unroll
    for (int tt = 0; tt < 2; ++tt) bcol[tt] = bias[wave * 32 + 2 * r16 + tt];

    __syncthreads();   // drains lgkm (A1 written); A2 already resident

    // ---- (5) MFMA: kc<4 A1*Wrel, kc>=4 A2*Wroot ----
    floatx4 acc[2][2];
#pragma unroll
    for (int r = 0; r < 2; ++r)
#pragma unroll
        for (int tt = 0; tt < 2; ++tt) acc[r][tt] = (floatx4){0.f, 0.f, 0.f, 0.f};

#pragma unroll
    for (int kc = 0; kc < 8; ++kc) {
        int m = kc >> 2;
        short8 af[2];
#pragma unroll
        for (int r = 0; r < 2; ++r) {
            int row = r * 16 + r16;
            int slot = ((kc & 3) * 4 + q) ^ r16;       // row&15 == r16
            af[r] = *(const short8*)(&smem[m * 4096 + row * 128 + slot * 8]);
        }
#pragma unroll
        for (int r = 0; r < 2; ++r) {
            acc[r][0] = __builtin_amdgcn_mfma_f32_16x16x32_bf16(af[r], wf[kc][0], acc[r][0], 0, 0, 0);
            acc[r][1] = __builtin_amdgcn_mfma_f32_16x16x32_bf16(af[r], wf[kc][1], acc[r][1], 0, 0, 0);
        }
    }

    // ---- epilogue: packed adjacent-col stores ----
    int colb = wave * 32 + 2 * r16;
#pragma unroll
    for (int r = 0; r < 2; ++r)
#pragma unroll
        for (int rr = 0; rr < 4; ++rr) {
            int row = rb + r * 16 + q * 4 + rr;
            if (row < N) {
                float v0 = acc[r][0][rr] + bcol[0];
                float v1 = acc[r][1][rr] + bcol[1];
                if (leaky) {
                    v0 = v0 >= 0.f ? v0 : 0.1f * v0;
                    v1 = v1 >= 0.f ? v1 : 0.1f * v1;
                }
                if (OUT_BF16) {
                    __hip_bfloat162 o;
                    o.x = __float2bfloat16(v0);
                    o.y = __float2bfloat16(v1);
                    *(__hip_bfloat162*)((__hip_bfloat16*)outv + (size_t)row * WW + colb) = o;
                } else {
                    float2 rv = *(const float2*)(resid + (size_t)row * WW + colb);
                    float2 o;
                    o.x = v0 + rv.x;
                    o.y = v1 + rv.y;
                    *(float2*)((float*)outv + (size_t)row * WW + colb) = o;
                }
            }
        }
}

extern "C" void kernel_launch(void* const* d_in, const int* in_sizes, int n_in,
                              void* d_out, int out_size, void* d_ws, size_t ws_size,
                              hipStream_t stream) {
    const float* x      = (const float*)d_in[0];
    const int*   ei     = (const int*)d_in[1];
    const float* ew     = (const float*)d_in[2];
    const int*   batch  = (const int*)d_in[3];
    const float* gnw    = (const float*)d_in[4];
    const float* gnb    = (const float*)d_in[5];
    const float* gnm    = (const float*)d_in[6];
    const float* Wrel1  = (const float*)d_in[7];
    const float* brel1  = (const float*)d_in[8];
    const float* Wroot1 = (const float*)d_in[9];
    const float* Wrel2  = (const float*)d_in[10];
    const float* brel2  = (const float*)d_in[11];
    const float* Wroot2 = (const float*)d_in[12];

    int N = in_sizes[0] / WW;
    int E = in_sizes[1] / 2;
    int P = (N + SCAN_B - 1) / SCAN_B;           // 98
    int ntiles = (N + 31) / 32;                  // 3125
    int HB = (E + 1023) / 1024;                  // hist blocks
    int SB = (N + 63) / 64;                      // stats blocks
    int PB = (E + 1023) / 1024;                  // place blocks
    int FB2 = (GG * WW + SCAN_B - 1) / SCAN_B;   // finalize blocks @1024 (8)
    int NB = (int)(((size_t)N * (WW / 8) + 255) / 256);   // normalize blocks

    // workspace layout (8-byte aligned):
    // xn | y1 (bf16 N*W each) | Wb (bf16 4*W*W) | ebuf (int2 E)
    // | deg | cursor | gsum | gsumsq | gcnt | scalev | shiftv | off | bsum
    __hip_bfloat16* xn = (__hip_bfloat16*)d_ws;
    __hip_bfloat16* y1 = xn + (size_t)N * WW;
    __hip_bfloat16* Wb = y1 + (size_t)N * WW;
    int2* ebuf   = (int2*)(Wb + 4 * WW * WW);
    int*  deg    = (int*)(ebuf + E);
    int*  cursor = deg + N;
    float* gsum   = (float*)(cursor + N);
    float* gsumsq = gsum + GG * WW;
    float* gcnt   = gsumsq + GG * WW;
    float* scalev = gcnt + GG;
    float* shiftv = scalev + GG * WW;
    int*  off    = (int*)(shiftv + GG * WW);
    int*  bsum   = off + N;

    hipMemsetAsync(deg, 0, ((size_t)2 * N + 2 * GG * WW + GG) * sizeof(int), stream);

    // ---- prep1: hist U stats U cvt_w ----
    prep1_kernel<<<HB + SB + 256, 256, 0, stream>>>(
        ei, E, deg, HB,
        x, batch, N, SB, gsum, gsumsq, gcnt,
        Wrel1, Wroot1, Wrel2, Wroot2, Wb);

    // ---- scan2: block scan U finalize ----
    scan2_kernel<<<P + FB2, SCAN_B, 0, stream>>>(
        deg, N, off, bsum, P,
        gsum, gsumsq, gcnt, gnw, gnb, gnm, scalev, shiftv);

    add_offsets2<<<P, SCAN_B, 0, stream>>>(off, bsum, N);

    // ---- place U normalize ----
    place_norm_kernel<<<PB + NB, 256, 0, stream>>>(
        ei, ew, off, cursor, ebuf, E, PB,
        x, batch, scalev, shiftv, xn, N);

    // ---- layer 1: fused gather+GEMM (+bias+leaky) ----
    fused_kernel<true><<<ntiles, 256, 0, stream>>>(
        xn, ebuf, off, deg, Wb, Wb + WW * WW, brel1, nullptr, y1, N, 1);

    // ---- layer 2: fused gather+GEMM (+bias+residual) ----
    fused_kernel<false><<<ntiles, 256, 0, stream>>>(
        y1, ebuf, off, deg, Wb + 2 * WW * WW, Wb + 3 * WW * WW, brel2, x, d_out, N, 0);
}

// Round 11
// 309.480 us; speedup vs baseline: 3.5522x; 1.0105x over previous
//
#include <hip/hip_runtime.h>
#include <hip/hip_bf16.h>

#define WW 128
#define GG 64
#define GN_EPS 1e-5f
#define SCAN_B 1024

typedef __attribute__((ext_vector_type(8))) short short8;
typedef __attribute__((ext_vector_type(4))) float floatx4;

__device__ inline float bfbits2f(short v) {
    return __uint_as_float(((unsigned)(unsigned short)v) << 16);
}
__device__ inline short f2bfbits(float f) {
    __hip_bfloat16 h = __float2bfloat16(f);
    return *reinterpret_cast<short*>(&h);
}

// ---------------- prep1: hist (4 edges/thread) U stats (64 rows) U cvt_w ----
__global__ __launch_bounds__(256) void prep1_kernel(
    const int* __restrict__ ei, int E, int* __restrict__ deg, int HB,
    const float* __restrict__ x, const int* __restrict__ batch, int N, int SB,
    float* __restrict__ gsum, float* __restrict__ gsumsq, float* __restrict__ gcnt,
    const float* __restrict__ w0, const float* __restrict__ w1,
    const float* __restrict__ w2, const float* __restrict__ w3,
    __hip_bfloat16* __restrict__ wdst)
{
    int bid = blockIdx.x;
    int tid = threadIdx.x;

    if (bid < HB) {
        int base = bid * 1024 + tid;
        int d0 = (base       < E) ? ei[(size_t)E + base]       : -1;
        int d1 = (base + 256 < E) ? ei[(size_t)E + base + 256] : -1;
        int d2 = (base + 512 < E) ? ei[(size_t)E + base + 512] : -1;
        int d3 = (base + 768 < E) ? ei[(size_t)E + base + 768] : -1;
        if (d0 >= 0) atomicAdd(&deg[d0], 1);
        if (d1 >= 0) atomicAdd(&deg[d1], 1);
        if (d2 >= 0) atomicAdd(&deg[d2], 1);
        if (d3 >= 0) atomicAdd(&deg[d3], 1);
        return;
    }
    if (bid < HB + SB) {
        int sb = bid - HB;
        int half = tid >> 7;
        int w = tid & 127;
        int row0 = sb * 64 + half * 32;
        if (row0 >= N) return;
        int row1 = min(row0 + 32, N);
        float s = 0.f, ss = 0.f;
        int cur = batch[row0];
        int cnt = 0;
        auto flush = [&]() {
            atomicAdd(&gsum[cur * WW + w], s);
            atomicAdd(&gsumsq[cur * WW + w], ss);
            if (w == 0) atomicAdd(&gcnt[cur], (float)cnt);
            s = 0.f; ss = 0.f; cnt = 0;
        };
        int i = row0;
        for (; i + 4 <= row1; i += 4) {
            int g0 = batch[i + 0], g1 = batch[i + 1], g2 = batch[i + 2], g3 = batch[i + 3];
            float v0 = x[(size_t)(i + 0) * WW + w];
            float v1 = x[(size_t)(i + 1) * WW + w];
            float v2 = x[(size_t)(i + 2) * WW + w];
            float v3 = x[(size_t)(i + 3) * WW + w];
            if (g0 != cur) { flush(); cur = g0; }
            s += v0; ss += v0 * v0; ++cnt;
            if (g1 != cur) { flush(); cur = g1; }
            s += v1; ss += v1 * v1; ++cnt;
            if (g2 != cur) { flush(); cur = g2; }
            s += v2; ss += v2 * v2; ++cnt;
            if (g3 != cur) { flush(); cur = g3; }
            s += v3; ss += v3 * v3; ++cnt;
        }
        for (; i < row1; ++i) {
            int g = batch[i];
            float v = x[(size_t)i * WW + w];
            if (g != cur) { flush(); cur = g; }
            s += v; ss += v * v; ++cnt;
        }
        flush();
        return;
    }
    int idx = (bid - HB - SB) * 256 + tid;        // 0 .. 65535
    int m = idx >> 14;
    int o = idx & 16383;
    const float* src = (m == 0) ? w0 : (m == 1) ? w1 : (m == 2) ? w2 : w3;
    wdst[idx] = __float2bfloat16(src[o]);
}

// ---------------- scan2: block-local scan U finalize (independent chains) ----
__global__ __launch_bounds__(SCAN_B) void scan2_kernel(
    const int* __restrict__ deg, int N, int* __restrict__ off, int* __restrict__ bsum, int P,
    const float* __restrict__ gsum, const float* __restrict__ gsumsq,
    const float* __restrict__ gcnt,
    const float* __restrict__ wgt, const float* __restrict__ bias,
    const float* __restrict__ ms,
    float* __restrict__ scalev, float* __restrict__ shiftv)
{
    int bid = blockIdx.x;
    int t = threadIdx.x;
    if (bid < P) {
        __shared__ int s[SCAN_B];
        int i = bid * SCAN_B + t;
        int v = (i < N) ? deg[i] : 0;
        s[t] = v; __syncthreads();
        for (int d = 1; d < SCAN_B; d <<= 1) {
            int tmp = (t >= d) ? s[t - d] : 0;
            __syncthreads();
            s[t] += tmp;
            __syncthreads();
        }
        if (i < N) off[i] = s[t] - v;
        if (t == SCAN_B - 1) bsum[bid] = s[t];
        return;
    }
    int idx = (bid - P) * SCAN_B + t;
    if (idx >= GG * WW) return;
    int g = idx >> 7, w = idx & (WW - 1);
    float cnt = gcnt[g];
    float inv = cnt > 0.f ? 1.f / cnt : 0.f;
    float mean = gsum[idx] * inv;
    float msw = ms[w];
    float var = gsumsq[idx] * inv - mean * mean * msw * (2.f - msw);
    var = fmaxf(var, 0.f);
    float sc = wgt[w] * rsqrtf(var + GN_EPS);
    scalev[idx] = sc;
    shiftv[idx] = bias[w] - sc * msw * mean;
}

// add_offsets v3: 64-lane shfl reduction over bsum[0..bid) (one barrier,
// replaces the 10-barrier 1024-wide tree over <=98 values).
__global__ __launch_bounds__(SCAN_B) void add_offsets2(
    int* __restrict__ off, const int* __restrict__ bsum, int N)
{
    __shared__ int red0;
    int t = threadIdx.x;
    if (t < 64) {
        int s = 0;
        for (int i = t; i < blockIdx.x; i += 64) s += bsum[i];
#pragma unroll
        for (int o = 32; o > 0; o >>= 1) s += __shfl_down(s, o, 64);
        if (t == 0) red0 = s;
    }
    __syncthreads();
    int i = blockIdx.x * SCAN_B + t;
    if (i < N) off[i] += red0;
}

// ---------------- place_norm: place (4 edges/thread) U normalize ----------
__global__ __launch_bounds__(256) void place_norm_kernel(
    const int* __restrict__ ei, const float* __restrict__ ew,
    const int* __restrict__ off, int* __restrict__ cursor,
    int2* __restrict__ ebuf, int E, int PB,
    const float* __restrict__ x, const int* __restrict__ batch,
    const float* __restrict__ scalev, const float* __restrict__ shiftv,
    __hip_bfloat16* __restrict__ xn, int N)
{
    int bid = blockIdx.x;
    int tid = threadIdx.x;

    if (bid < PB) {
        int base = bid * 1024 + tid;
        int dstv[4], srcv[4];
        float wv[4];
        int slot[4];
#pragma unroll
        for (int i = 0; i < 4; ++i) {
            int e = base + i * 256;
            dstv[i] = (e < E) ? ei[(size_t)E + e] : -1;
        }
#pragma unroll
        for (int i = 0; i < 4; ++i) {
            int e = base + i * 256;
            if (e < E) { srcv[i] = ei[e]; wv[i] = ew[e]; }
        }
#pragma unroll
        for (int i = 0; i < 4; ++i)
            if (dstv[i] >= 0) slot[i] = off[dstv[i]] + atomicAdd(&cursor[dstv[i]], 1);
#pragma unroll
        for (int i = 0; i < 4; ++i)
            if (dstv[i] >= 0) {
                unsigned long long v = (unsigned)srcv[i]
                    | ((unsigned long long)__float_as_uint(wv[i]) << 32);
                __builtin_nontemporal_store(v, (unsigned long long*)&ebuf[slot[i]]);
            }
        return;
    }
    // ---- normalize: one thread per 8 elems, 16B stores ----
    size_t nt = (size_t)(bid - PB) * 256 + tid;
    if (nt >= (size_t)N * (WW / 8)) return;
    int row = (int)(nt >> 4);
    int c8 = (int)(nt & 15) * 8;
    int g = batch[row];
    const float* xb = x + (size_t)row * WW + c8;
    const float* scb = scalev + (size_t)g * WW + c8;
    const float* shb = shiftv + (size_t)g * WW + c8;
    float4 v0 = *(const float4*)(xb);
    float4 v1 = *(const float4*)(xb + 4);
    float4 sc0 = *(const float4*)(scb);
    float4 sc1 = *(const float4*)(scb + 4);
    float4 sh0 = *(const float4*)(shb);
    float4 sh1 = *(const float4*)(shb + 4);
    union { short s[8]; uint4 u; } pk;
    pk.s[0] = f2bfbits(sc0.x * v0.x + sh0.x);
    pk.s[1] = f2bfbits(sc0.y * v0.y + sh0.y);
    pk.s[2] = f2bfbits(sc0.z * v0.z + sh0.z);
    pk.s[3] = f2bfbits(sc0.w * v0.w + sh0.w);
    pk.s[4] = f2bfbits(sc1.x * v1.x + sh1.x);
    pk.s[5] = f2bfbits(sc1.y * v1.y + sh1.y);
    pk.s[6] = f2bfbits(sc1.z * v1.z + sh1.z);
    pk.s[7] = f2bfbits(sc1.w * v1.w + sh1.w);
    *(uint4*)(xn + (size_t)row * WW + c8) = pk.u;
}

// ---------------- fused gather+GEMM v13: v11 core + 6 blocks/CU -------------
// v11 core unchanged (R8/R10-verified, 62.5 us). Single change: launch_bounds
// (256,4)->(256,6). R10 counters: occupancy capped at 43% by the 4-blocks/CU
// bound while VGPR=48 (cap ~85 at 6 waves/EU) and LDS 20.5KB (6x=123KB<160KB)
// have headroom. Gather is latency/MLP-bound (fabric ~4.7 TB/s < ceiling);
// +50% co-resident blocks -> +50% outstanding row reads per CU.
// LDS swizzle (involution): slot s of row r holds chunk s^(r&15).
// C/D layout: col=lane&15, row=(lane>>4)*4+reg (m89-verified).
template <bool OUT_BF16>
__global__ __launch_bounds__(256, 6) void fused_kernel(
    const __hip_bfloat16* __restrict__ X,
    const int2* __restrict__ ebuf, const int* __restrict__ off,
    const int* __restrict__ deg,
    const __hip_bfloat16* __restrict__ Wrel, const __hip_bfloat16* __restrict__ Wroot,
    const float* __restrict__ bias, const float* __restrict__ resid,
    void* __restrict__ outv, int N, int leaky)
{
    __shared__ __align__(16) __hip_bfloat16 smem[2 * 32 * 128];   // 16 KB
    __shared__ __align__(16) int2 eshare[512];                    // 4 KB
    int tid = threadIdx.x;
    int wave = tid >> 6, lane = tid & 63;
    int q = lane >> 4, r16 = lane & 15;
    int rb = blockIdx.x * 32;

    // ---- (1a) A2 staging: 8 x 1KB instructions, 2 per wave (async) ----
#pragma unroll
    for (int s = 0; s < 2; ++s) {
        int t = wave * 2 + s;                     // 0..7, rows t*4..t*4+3
        int rloc = t * 4 + (lane >> 4);
        int c = (lane & 15) ^ (rloc & 15);        // pre-swizzled global chunk
        int grow = rb + rloc; if (grow >= N) grow = N - 1;
        const __hip_bfloat16* g = X + (size_t)grow * WW + c * 8;
        __hip_bfloat16* l = smem + 4096 + t * 512;   // linear LDS dest
        __builtin_amdgcn_global_load_lds(
            (const __attribute__((address_space(1))) void*)g,
            (__attribute__((address_space(3))) void*)l, 16, 0, 0);
    }

    // ---- (1b) ebuf slice staging: entries [e0, e0+nstage) -> eshare ----
    int endn = min(rb + 32, N) - 1;
    int e0 = off[rb];
    int ne = off[endn] + deg[endn] - e0;
    int nstage = min(ne, 512);
    {
        int pairs = (nstage + 1) >> 1;            // <= 256: one instr/thread
        if (tid < pairs) {
            const int2* g = ebuf + e0 + 2 * tid;
            int2* l = eshare + 2 * (wave * 64);
            __builtin_amdgcn_global_load_lds(
                (const __attribute__((address_space(1))) void*)g,
                (__attribute__((address_space(3))) void*)l, 16, 0, 0);
        }
    }
    __syncthreads();   // vmcnt(0): A2 + edge slice resident

    // ---- (2) gather: node = rb + tid>>3, cols (tid&7)*16..+15 ----
    int node = rb + (tid >> 3);
    int nc = node < N ? node : N - 1;
    int start = off[nc];
    int d = (node < N) ? deg[nc] : 0;
    int lb = start - e0;                          // local index into eshare
    int sub = tid & 7;
    float a16[16];
#pragma unroll
    for (int j = 0; j < 16; ++j) a16[j] = 0.f;
    int last = d - 1;                             // d==0 -> loop skipped
    for (int k = 0; k <= last; k += 4) {
        int j1 = min(k + 1, last);
        int j2 = min(k + 2, last);
        int j3 = min(k + 3, last);
        int2 p0, p1, p2, p3;
        if (lb + j3 < nstage) {                   // common case: all staged
            p0 = eshare[lb + k];
            p1 = eshare[lb + j1];
            p2 = eshare[lb + j2];
            p3 = eshare[lb + j3];
        } else {                                  // ~never (block ne > 512)
            p0 = (lb + k  < nstage) ? eshare[lb + k]  : ebuf[start + k];
            p1 = (lb + j1 < nstage) ? eshare[lb + j1] : ebuf[start + j1];
            p2 = (lb + j2 < nstage) ? eshare[lb + j2] : ebuf[start + j2];
            p3 = (lb + j3 < nstage) ? eshare[lb + j3] : ebuf[start + j3];
        }
        const __hip_bfloat16* r0 = X + (size_t)p0.x * WW + sub * 16;
        const __hip_bfloat16* r1 = X + (size_t)p1.x * WW + sub * 16;
        const __hip_bfloat16* r2 = X + (size_t)p2.x * WW + sub * 16;
        const __hip_bfloat16* r3 = X + (size_t)p3.x * WW + sub * 16;
        short8 a0 = *(const short8*)(r0);
        short8 b0 = *(const short8*)(r0 + 8);
        short8 a1 = *(const short8*)(r1);
        short8 b1 = *(const short8*)(r1 + 8);
        short8 a2 = *(const short8*)(r2);
        short8 b2 = *(const short8*)(r2 + 8);
        short8 a3 = *(const short8*)(r3);
        short8 b3 = *(const short8*)(r3 + 8);
        float w0 = __int_as_float(p0.y);
        float w1 = (k + 1 <= last) ? __int_as_float(p1.y) : 0.f;
        float w2 = (k + 2 <= last) ? __int_as_float(p2.y) : 0.f;
        float w3 = (k + 3 <= last) ? __int_as_float(p3.y) : 0.f;
#pragma unroll
        for (int j = 0; j < 8; ++j) {
            a16[j]     += w0 * bfbits2f(a0[j]) + w1 * bfbits2f(a1[j]);
            a16[8 + j] += w0 * bfbits2f(b0[j]) + w1 * bfbits2f(b1[j]);
            a16[j]     += w2 * bfbits2f(a2[j]) + w3 * bfbits2f(a3[j]);
            a16[8 + j] += w2 * bfbits2f(b2[j]) + w3 * bfbits2f(b3[j]);
        }
    }

    // ---- (3) agg -> A1 LDS region, swizzled (chunks 2*sub, 2*sub+1) ----
    {
        int r = tid >> 3;                          // local row 0..31
        short8 pk0, pk1;
#pragma unroll
        for (int j = 0; j < 8; ++j) {
            pk0[j] = f2bfbits(a16[j]);
            pk1[j] = f2bfbits(a16[8 + j]);
        }
        int s0 = (2 * sub)     ^ (r & 15);
        int s1 = (2 * sub + 1) ^ (r & 15);
        *(short8*)(smem + r * 128 + s0 * 8) = pk0;
        *(short8*)(smem + r * 128 + s1 * 8) = pk1;
    }

    // ---- W fragments: adjacent-pair cols (wave*32 + 2*r16 + tt) ----
    short8 wf[8][2];
#pragma unroll
    for (int kc = 0; kc < 8; ++kc) {
        const __hip_bfloat16* Wsel = (kc < 4) ? Wrel : Wroot;
        int koff = (kc & 3) * 32 + q * 8;
#pragma unroll
        for (int tt = 0; tt < 2; ++tt) {
            int col = wave * 32 + 2 * r16 + tt;
            wf[kc][tt] = *(const short8*)(Wsel + ((size_t)col * WW + koff));
        }
    }
    float bcol[2];
#pragma unroll
    for (int tt = 0; tt < 2; ++tt) bcol[tt] = bias[wave * 32 + 2 * r16 + tt];

    __syncthreads();   // drains lgkm (A1 written); A2 already resident

    // ---- (5) MFMA: kc<4 A1*Wrel, kc>=4 A2*Wroot ----
    floatx4 acc[2][2];
#pragma unroll
    for (int r = 0; r < 2; ++r)
#pragma unroll
        for (int tt = 0; tt < 2; ++tt) acc[r][tt] = (floatx4){0.f, 0.f, 0.f, 0.f};

#pragma unroll
    for (int kc = 0; kc < 8; ++kc) {
        int m = kc >> 2;
        short8 af[2];
#pragma unroll
        for (int r = 0; r < 2; ++r) {
            int row = r * 16 + r16;
            int slot = ((kc & 3) * 4 + q) ^ r16;       // row&15 == r16
            af[r] = *(const short8*)(&smem[m * 4096 + row * 128 + slot * 8]);
        }
#pragma unroll
        for (int r = 0; r < 2; ++r) {
            acc[r][0] = __builtin_amdgcn_mfma_f32_16x16x32_bf16(af[r], wf[kc][0], acc[r][0], 0, 0, 0);
            acc[r][1] = __builtin_amdgcn_mfma_f32_16x16x32_bf16(af[r], wf[kc][1], acc[r][1], 0, 0, 0);
        }
    }

    // ---- epilogue: packed adjacent-col stores ----
    int colb = wave * 32 + 2 * r16;
#pragma unroll
    for (int r = 0; r < 2; ++r)
#pragma unroll
        for (int rr = 0; rr < 4; ++rr) {
            int row = rb + r * 16 + q * 4 + rr;
            if (row < N) {
                float v0 = acc[r][0][rr] + bcol[0];
                float v1 = acc[r][1][rr] + bcol[1];
                if (leaky) {
                    v0 = v0 >= 0.f ? v0 : 0.1f * v0;
                    v1 = v1 >= 0.f ? v1 : 0.1f * v1;
                }
                if (OUT_BF16) {
                    __hip_bfloat162 o;
                    o.x = __float2bfloat16(v0);
                    o.y = __float2bfloat16(v1);
                    *(__hip_bfloat162*)((__hip_bfloat16*)outv + (size_t)row * WW + colb) = o;
                } else {
                    float2 rv = *(const float2*)(resid + (size_t)row * WW + colb);
                    float2 o;
                    o.x = v0 + rv.x;
                    o.y = v1 + rv.y;
                    *(float2*)((float*)outv + (size_t)row * WW + colb) = o;
                }
            }
        }
}

extern "C" void kernel_launch(void* const* d_in, const int* in_sizes, int n_in,
                              void* d_out, int out_size, void* d_ws, size_t ws_size,
                              hipStream_t stream) {
    const float* x      = (const float*)d_in[0];
    const int*   ei     = (const int*)d_in[1];
    const float* ew     = (const float*)d_in[2];
    const int*   batch  = (const int*)d_in[3];
    const float* gnw    = (const float*)d_in[4];
    const float* gnb    = (const float*)d_in[5];
    const float* gnm    = (const float*)d_in[6];
    const float* Wrel1  = (const float*)d_in[7];
    const float* brel1  = (const float*)d_in[8];
    const float* Wroot1 = (const float*)d_in[9];
    const float* Wrel2  = (const float*)d_in[10];
    const float* brel2  = (const float*)d_in[11];
    const float* Wroot2 = (const float*)d_in[12];

    int N = in_sizes[0] / WW;
    int E = in_sizes[1] / 2;
    int P = (N + SCAN_B - 1) / SCAN_B;           // 98
    int ntiles = (N + 31) / 32;                  // 3125
    int HB = (E + 1023) / 1024;                  // hist blocks
    int SB = (N + 63) / 64;                      // stats blocks
    int PB = (E + 1023) / 1024;                  // place blocks
    int FB2 = (GG * WW + SCAN_B - 1) / SCAN_B;   // finalize blocks @1024 (8)
    int NB = (int)(((size_t)N * (WW / 8) + 255) / 256);   // normalize blocks

    // workspace layout (8-byte aligned):
    // xn | y1 (bf16 N*W each) | Wb (bf16 4*W*W) | ebuf (int2 E)
    // | deg | cursor | gsum | gsumsq | gcnt | scalev | shiftv | off | bsum
    __hip_bfloat16* xn = (__hip_bfloat16*)d_ws;
    __hip_bfloat16* y1 = xn + (size_t)N * WW;
    __hip_bfloat16* Wb = y1 + (size_t)N * WW;
    int2* ebuf   = (int2*)(Wb + 4 * WW * WW);
    int*  deg    = (int*)(ebuf + E);
    int*  cursor = deg + N;
    float* gsum   = (float*)(cursor + N);
    float* gsumsq = gsum + GG * WW;
    float* gcnt   = gsumsq + GG * WW;
    float* scalev = gcnt + GG;
    float* shiftv = scalev + GG * WW;
    int*  off    = (int*)(shiftv + GG * WW);
    int*  bsum   = off + N;

    hipMemsetAsync(deg, 0, ((size_t)2 * N + 2 * GG * WW + GG) * sizeof(int), stream);

    // ---- prep1: hist U stats U cvt_w ----
    prep1_kernel<<<HB + SB + 256, 256, 0, stream>>>(
        ei, E, deg, HB,
        x, batch, N, SB, gsum, gsumsq, gcnt,
        Wrel1, Wroot1, Wrel2, Wroot2, Wb);

    // ---- scan2: block scan U finalize ----
    scan2_kernel<<<P + FB2, SCAN_B, 0, stream>>>(
        deg, N, off, bsum, P,
        gsum, gsumsq, gcnt, gnw, gnb, gnm, scalev, shiftv);

    add_offsets2<<<P, SCAN_B, 0, stream>>>(off, bsum, N);

    // ---- place U normalize ----
    place_norm_kernel<<<PB + NB, 256, 0, stream>>>(
        ei, ew, off, cursor, ebuf, E, PB,
        x, batch, scalev, shiftv, xn, N);

    // ---- layer 1: fused gather+GEMM (+bias+leaky) ----
    fused_kernel<true><<<ntiles, 256, 0, stream>>>(
        xn, ebuf, off, deg, Wb, Wb + WW * WW, brel1, nullptr, y1, N, 1);

    // ---- layer 2: fused gather+GEMM (+bias+residual) ----
    fused_kernel<false><<<ntiles, 256, 0, stream>>>(
        y1, ebuf, off, deg, Wb + 2 * WW * WW, Wb + 3 * WW * WW, brel2, x, d_out, N, 0);
}